// Round 3
// baseline (781.885 us; speedup 1.0000x reference)
//
#include <hip/hip_runtime.h>
#include <math.h>

#define BB 64
#define SS 4096
#define DD 512

// t[b,d] = sum_k topic[b,k] * W[k,d]
// grid: 64 b * 4 d-chunks = 256 blocks; block 256 threads.
__global__ __launch_bounds__(256) void tW_kernel(const float* __restrict__ topic,
                                                 const float* __restrict__ W,
                                                 float* __restrict__ t) {
    __shared__ float tp[DD];
    __shared__ float4 part[256];
    const int b      = blockIdx.x >> 2;
    const int dchunk = (blockIdx.x & 3) * 32;   // in float4 units (32 f4 = 128 floats)
    const int dg     = threadIdx.x & 31;        // float4 group within chunk
    const int strip  = threadIdx.x >> 5;        // 0..7, each owns 64 k
    for (int i = threadIdx.x; i < DD; i += 256) tp[i] = topic[b * DD + i];
    __syncthreads();
    const float4* W4 = (const float4*)W;        // row stride 128 float4
    float4 acc = {0.f, 0.f, 0.f, 0.f};
    const int k0 = strip * 64;
#pragma unroll 8
    for (int k = 0; k < 64; ++k) {
        const float s  = tp[k0 + k];
        const float4 w = W4[(size_t)(k0 + k) * 128 + dchunk + dg];
        acc.x += s * w.x; acc.y += s * w.y; acc.z += s * w.z; acc.w += s * w.w;
    }
    part[threadIdx.x] = acc;
    __syncthreads();
    if (threadIdx.x < 32) {
        float4 r = part[threadIdx.x];
#pragma unroll
        for (int st = 1; st < 8; ++st) {
            const float4 q = part[st * 32 + threadIdx.x];
            r.x += q.x; r.y += q.y; r.z += q.z; r.w += q.w;
        }
        ((float4*)(t + b * DD))[dchunk + dg] = r;
    }
}

// scores[b,s] = t[b] . seq[b,s] + bias
// v3 (unchanged this round): direct streaming, 16 rows/wave, private
// partials, 17-shuffle wave fold. Measured-equal to v1 => believed BW-bound.
__global__ __launch_bounds__(256) void scores_kernel(const float* __restrict__ t,
                                                     const float* __restrict__ seq,
                                                     const float* __restrict__ bias,
                                                     float* __restrict__ scores) {
    const int b    = blockIdx.y;
    const int wave = threadIdx.x >> 6;
    const int lane = threadIdx.x & 63;
    const int s0   = blockIdx.x * 64 + wave * 16;   // 16 rows per wave

    const float4* trow = (const float4*)(t + (size_t)b * DD);
    const float4 ta = trow[lane];
    const float4 tb = trow[lane + 64];

    const float4* base = (const float4*)(seq + ((size_t)b * SS + s0) * DD);

    float acc[16];
#pragma unroll
    for (int r = 0; r < 16; ++r) {
        const float4* p = base + (size_t)r * 128;
        const float4 a = p[lane];
        const float4 c = p[lane + 64];
        acc[r] = a.x * ta.x + a.y * ta.y + a.z * ta.z + a.w * ta.w
               + c.x * tb.x + c.y * tb.y + c.z * tb.z + c.w * tb.w;
    }

#pragma unroll
    for (int i = 0; i < 8; ++i) {
        const float s = (lane & 1) ? acc[i] : acc[i + 8];
        const float y = __shfl_xor(s, 1, 64);
        acc[i] = ((lane & 1) ? acc[i + 8] : acc[i]) + y;
    }
#pragma unroll
    for (int i = 0; i < 4; ++i) {
        const float s = (lane & 2) ? acc[i] : acc[i + 4];
        const float y = __shfl_xor(s, 2, 64);
        acc[i] = ((lane & 2) ? acc[i + 4] : acc[i]) + y;
    }
#pragma unroll
    for (int i = 0; i < 2; ++i) {
        const float s = (lane & 4) ? acc[i] : acc[i + 2];
        const float y = __shfl_xor(s, 4, 64);
        acc[i] = ((lane & 4) ? acc[i + 2] : acc[i]) + y;
    }
    {
        const float s = (lane & 8) ? acc[0] : acc[1];
        const float y = __shfl_xor(s, 8, 64);
        acc[0] = ((lane & 8) ? acc[1] : acc[0]) + y;
    }
    acc[0] += __shfl_xor(acc[0], 16, 64);
    acc[0] += __shfl_xor(acc[0], 32, 64);

    if (lane < 16) {
        const int r = ((lane & 1) << 3) | ((lane & 2) << 1)
                    | ((lane & 4) >> 1) | ((lane & 8) >> 3);
        scores[(size_t)b * SS + s0 + r] = acc[0] + bias[0];
    }
}

// row softmax over S=4096, one block of 1024 threads per row (float4/thread)
__global__ __launch_bounds__(1024) void softmax_kernel(const float* __restrict__ scores,
                                                       float* __restrict__ out) {
    __shared__ float red[16];
    const int b   = blockIdx.x;
    const int tid = threadIdx.x;
    const int wave = tid >> 6, lane = tid & 63;

    const float4 v = ((const float4*)(scores + (size_t)b * SS))[tid];

    float m = fmaxf(fmaxf(v.x, v.y), fmaxf(v.z, v.w));
#pragma unroll
    for (int k = 32; k; k >>= 1) m = fmaxf(m, __shfl_xor(m, k, 64));
    if (lane == 0) red[wave] = m;
    __syncthreads();
    if (tid < 16) {
        float x = red[tid];
#pragma unroll
        for (int k = 8; k; k >>= 1) x = fmaxf(x, __shfl_xor(x, k, 16));
        if (tid == 0) red[0] = x;
    }
    __syncthreads();
    m = red[0];
    __syncthreads();

    float4 e;
    e.x = __expf(v.x - m); e.y = __expf(v.y - m);
    e.z = __expf(v.z - m); e.w = __expf(v.w - m);
    float s = e.x + e.y + e.z + e.w;
#pragma unroll
    for (int k = 32; k; k >>= 1) s += __shfl_xor(s, k, 64);
    if (lane == 0) red[wave] = s;
    __syncthreads();
    if (tid < 16) {
        float x = red[tid];
#pragma unroll
        for (int k = 8; k; k >>= 1) x += __shfl_xor(x, k, 16);
        if (tid == 0) red[0] = x;
    }
    __syncthreads();
    const float inv = 1.f / red[0];

    float4 o;
    o.x = e.x * inv; o.y = e.y * inv; o.z = e.z * inv; o.w = e.w * inv;
    ((float4*)(out + (size_t)b * SS))[tid] = o;
}

extern "C" void kernel_launch(void* const* d_in, const int* in_sizes, int n_in,
                              void* d_out, int out_size, void* d_ws, size_t ws_size,
                              hipStream_t stream) {
    const float* topic = (const float*)d_in[0];   // [B, D]
    const float* seq   = (const float*)d_in[1];   // [B, S, D]
    const float* W     = (const float*)d_in[2];   // [D, D]
    const float* bias  = (const float*)d_in[3];   // [1]
    float* out = (float*)d_out;                   // [B, S]

    float* t      = (float*)d_ws;                 // B*D floats
    float* scores = t + BB * DD;                  // B*S floats

    // PROBE ROUND: enqueue the full pipeline TWICE. Pass 2 recomputes
    // bit-identical results from the inputs (deterministic, no atomics),
    // so correctness/absmax are unchanged. dur_us delta vs previous round
    // == marginal in-graph cost of one full kernel pipeline, resolving
    // whether the ~550 us residual is harness poison fill (H1) or
    // kernel-side slack (H2).
    for (int rep = 0; rep < 2; ++rep) {
        tW_kernel<<<dim3(BB * 4), 256, 0, stream>>>(topic, W, t);
        scores_kernel<<<dim3(SS / 64, BB), 256, 0, stream>>>(t, seq, bias, scores);
        softmax_kernel<<<dim3(BB), 1024, 0, stream>>>(scores, out);
    }
}